// Round 1
// baseline (2697.750 us; speedup 1.0000x reference)
//
#include <hip/hip_runtime.h>
#include <stdint.h>

// ---------------------------------------------------------------------------
// ActorCriticRNN on MI355X.
// Pipeline:
//   prep:  transpose/convert weights to bf16 (B^T layout for MFMA), build
//          Wh in MFMA-fragment-linear layout for the register-resident GRU.
//   G1:    emb = relu(obs @ W_emb + b_emb)            bf16 MFMA 128x128 tile
//   G2:    gi  = emb @ Wi + bi   (hoisted out of scan) bf16 MFMA
//   GRU:   16 WGs x 16 batch rows, Wh register-resident (192 VGPR/thread of
//          B-fragments), h in LDS bf16, gi double-buffered in LDS. 512 steps,
//          no grid sync (batch rows are independent across WGs).
//   G3:    [a|c] = relu(y @ [W_a|W_c1] + [b_a|b_c1])  bf16 MFMA
//   G4:    logits = a @ [W_lc1|W_lc2|W_mc|W_hint] + b, masked by avail
//   G5:    critic = relu_c . W_c2 + b_c2 (wave dot + shuffle reduce)
//   out0:  hidden = y[T-1] -> fp32
// ---------------------------------------------------------------------------

typedef short short8 __attribute__((ext_vector_type(8)));
typedef float f32x4  __attribute__((ext_vector_type(4)));

#define T_DIM 512
#define B_DIM 256
#define TBROWS 131072           // T*B

// output offsets (fp32 elements)
#define OUT_HID  ((size_t)0)
#define OUT_LC1  ((size_t)65536)
#define OUT_LC2  ((size_t)4259840)
#define OUT_MC   ((size_t)8454144)
#define OUT_HINT ((size_t)10551296)
#define OUT_CRIT ((size_t)18939904)

__device__ __forceinline__ unsigned short f2bf(float f) {
    unsigned u = __float_as_uint(f);
    u += 0x7fffu + ((u >> 16) & 1u);          // round-to-nearest-even
    return (unsigned short)(u >> 16);
}
__device__ __forceinline__ float bf2f(unsigned short h) {
    return __uint_as_float(((unsigned)h) << 16);
}

// ---------------------------------------------------------------------------
// prep: weight conversion / transposition / fragment-layout packing
//   [0,131072)          WembT[256][512]
//   [131072,327680)     WiT[768][256]
//   [327680,524288)     WhF fragment-linear (see k_gru for exact inverse)
//   [524288,655360)     WacT[512][256]  (W_a rows 0..255, W_c1 rows 256..511)
//   [655360,696320)     WlogT[160][256] (lc1|lc2|mc|hint|zero-pad)
//   [696320,696480)     blog[160]
// ---------------------------------------------------------------------------
__global__ __launch_bounds__(256, 4) void k_prep(
    const float* __restrict__ W_emb, const float* __restrict__ Wi,
    const float* __restrict__ Wh,    const float* __restrict__ W_a,
    const float* __restrict__ W_c1,  const float* __restrict__ W_lc1,
    const float* __restrict__ W_lc2, const float* __restrict__ W_mc,
    const float* __restrict__ W_hint,
    const float* __restrict__ b_lc1, const float* __restrict__ b_lc2,
    const float* __restrict__ b_mc,  const float* __restrict__ b_hint,
    unsigned short* __restrict__ WembT, unsigned short* __restrict__ WiT,
    unsigned short* __restrict__ WhF,   unsigned short* __restrict__ WacT,
    unsigned short* __restrict__ WlogT, float* __restrict__ blog)
{
    int i = blockIdx.x * 256 + threadIdx.x;
    if (i < 131072) {                         // WembT[n][k] = W_emb[k][n]
        int n = i >> 9, k = i & 511;
        WembT[i] = f2bf(W_emb[k * 256 + n]);
        return;
    }
    i -= 131072;
    if (i < 196608) {                         // WiT[n][k] = Wi[k][n]
        int n = i >> 8, k = i & 255;
        WiT[i] = f2bf(Wi[k * 768 + n]);
        return;
    }
    i -= 196608;
    if (i < 196608) {                         // Wh fragment-linear
        int jj = i & 7, L = (i >> 3) & 63, ks = (i >> 9) & 7, rest = i >> 12;
        int w = rest / 6, i6 = rest % 6, rho = i6 >> 1, s = i6 & 1;
        int k   = ks * 32 + ((L >> 4) << 3) + jj;
        int col = rho * 256 + w * 32 + s * 16 + (L & 15);
        WhF[i] = f2bf(Wh[k * 768 + col]);
        return;
    }
    i -= 196608;
    if (i < 131072) {                         // WacT
        int n = i >> 8, k = i & 255;
        WacT[i] = f2bf(n < 256 ? W_a[k * 256 + n] : W_c1[k * 256 + (n - 256)]);
        return;
    }
    i -= 131072;
    if (i < 40960) {                          // WlogT (N padded to 160)
        int n = i >> 8, k = i & 255;
        float v;
        if      (n < 32)  v = W_lc1[k * 32 + n];
        else if (n < 64)  v = W_lc2[k * 32 + (n - 32)];
        else if (n < 80)  v = W_mc [k * 16 + (n - 64)];
        else if (n < 144) v = W_hint[k * 64 + (n - 80)];
        else              v = 0.f;
        WlogT[i] = f2bf(v);
        return;
    }
    i -= 40960;
    if (i < 160) {                            // concatenated logit bias
        float v;
        if      (i < 32)  v = b_lc1[i];
        else if (i < 64)  v = b_lc2[i - 32];
        else if (i < 80)  v = b_mc [i - 64];
        else if (i < 144) v = b_hint[i - 80];
        else              v = 0.f;
        blog[i] = v;
    }
}

// ---------------------------------------------------------------------------
// G1: emb = relu(obs @ W_emb + b_emb).  A fp32 (converted during staging),
// B = WembT bf16.  M=TB, N=256, K=512.  128x128 tile, 4 waves, 4x4 acc each.
// ---------------------------------------------------------------------------
__global__ __launch_bounds__(256, 3) void k_gemm_obs(
    const float* __restrict__ A, const unsigned short* __restrict__ Bt,
    const float* __restrict__ bias, unsigned short* __restrict__ out)
{
    __shared__ unsigned short As[128][72];    // stride 72 (144 B) -> 2-way banks (free)
    __shared__ unsigned short Bs[128][72];
    const int tid = threadIdx.x, w = tid >> 6, L = tid & 63;
    const int mq = (w >> 1) * 64, nq = (w & 1) * 64;
    const int m0 = blockIdx.x * 128, n0 = blockIdx.y * 128;
    const int sr = tid >> 1, sh = (tid & 1) * 32;
    const int lc = L & 15, lq8 = (L >> 4) * 8, lr = (L >> 4) * 4;

    f32x4 acc[4][4];
#pragma unroll
    for (int i = 0; i < 4; i++)
#pragma unroll
        for (int j = 0; j < 4; j++) acc[i][j] = 0;

    const float* Ag = A + (size_t)(m0 + sr) * 512 + sh;
    const unsigned short* Bg = Bt + (size_t)(n0 + sr) * 512 + sh;

    for (int kt = 0; kt < 512; kt += 64) {
#pragma unroll
        for (int c = 0; c < 32; c += 8) {
            f32x4 v0 = *(const f32x4*)(Ag + kt + c);
            f32x4 v1 = *(const f32x4*)(Ag + kt + c + 4);
            short8 pk;
            pk[0] = (short)f2bf(v0[0]); pk[1] = (short)f2bf(v0[1]);
            pk[2] = (short)f2bf(v0[2]); pk[3] = (short)f2bf(v0[3]);
            pk[4] = (short)f2bf(v1[0]); pk[5] = (short)f2bf(v1[1]);
            pk[6] = (short)f2bf(v1[2]); pk[7] = (short)f2bf(v1[3]);
            *(short8*)&As[sr][sh + c] = pk;
            *(short8*)&Bs[sr][sh + c] = *(const short8*)(Bg + kt + c);
        }
        __syncthreads();
#pragma unroll
        for (int ks = 0; ks < 2; ks++) {
            short8 a[4], b[4];
#pragma unroll
            for (int i = 0; i < 4; i++)
                a[i] = *(const short8*)&As[mq + i * 16 + lc][ks * 32 + lq8];
#pragma unroll
            for (int j = 0; j < 4; j++)
                b[j] = *(const short8*)&Bs[nq + j * 16 + lc][ks * 32 + lq8];
#pragma unroll
            for (int i = 0; i < 4; i++)
#pragma unroll
                for (int j = 0; j < 4; j++)
                    acc[i][j] = __builtin_amdgcn_mfma_f32_16x16x32_bf16(a[i], b[j], acc[i][j], 0, 0, 0);
        }
        __syncthreads();
    }
#pragma unroll
    for (int i = 0; i < 4; i++)
#pragma unroll
        for (int j = 0; j < 4; j++) {
            int col = n0 + nq + j * 16 + lc;
            float bv = bias[col];
#pragma unroll
            for (int rg = 0; rg < 4; rg++) {
                int row = m0 + mq + i * 16 + lr + rg;
                float v = acc[i][j][rg] + bv;
                v = fmaxf(v, 0.f);
                out[(size_t)row * 256 + col] = f2bf(v);
            }
        }
}

// ---------------------------------------------------------------------------
// Generic bf16-A GEMM, K=256, M=TB.  Used for G2 (gi) and G3 (a|c).
// ---------------------------------------------------------------------------
__global__ __launch_bounds__(256, 3) void k_gemm_bf(
    const unsigned short* __restrict__ A, const unsigned short* __restrict__ Bt,
    const float* __restrict__ biasA, const float* __restrict__ biasB,
    int nsplit, int relu, int N, unsigned short* __restrict__ out)
{
    __shared__ unsigned short As[128][72];
    __shared__ unsigned short Bs[128][72];
    const int tid = threadIdx.x, w = tid >> 6, L = tid & 63;
    const int mq = (w >> 1) * 64, nq = (w & 1) * 64;
    const int m0 = blockIdx.x * 128, n0 = blockIdx.y * 128;
    const int sr = tid >> 1, sh = (tid & 1) * 32;
    const int lc = L & 15, lq8 = (L >> 4) * 8, lr = (L >> 4) * 4;

    f32x4 acc[4][4];
#pragma unroll
    for (int i = 0; i < 4; i++)
#pragma unroll
        for (int j = 0; j < 4; j++) acc[i][j] = 0;

    const unsigned short* Ag = A + (size_t)(m0 + sr) * 256 + sh;
    const unsigned short* Bg = Bt + (size_t)(n0 + sr) * 256 + sh;

    for (int kt = 0; kt < 256; kt += 64) {
#pragma unroll
        for (int c = 0; c < 32; c += 8) {
            *(short8*)&As[sr][sh + c] = *(const short8*)(Ag + kt + c);
            *(short8*)&Bs[sr][sh + c] = *(const short8*)(Bg + kt + c);
        }
        __syncthreads();
#pragma unroll
        for (int ks = 0; ks < 2; ks++) {
            short8 a[4], b[4];
#pragma unroll
            for (int i = 0; i < 4; i++)
                a[i] = *(const short8*)&As[mq + i * 16 + lc][ks * 32 + lq8];
#pragma unroll
            for (int j = 0; j < 4; j++)
                b[j] = *(const short8*)&Bs[nq + j * 16 + lc][ks * 32 + lq8];
#pragma unroll
            for (int i = 0; i < 4; i++)
#pragma unroll
                for (int j = 0; j < 4; j++)
                    acc[i][j] = __builtin_amdgcn_mfma_f32_16x16x32_bf16(a[i], b[j], acc[i][j], 0, 0, 0);
        }
        __syncthreads();
    }
#pragma unroll
    for (int i = 0; i < 4; i++)
#pragma unroll
        for (int j = 0; j < 4; j++) {
            int col = n0 + nq + j * 16 + lc;
            float bv = (col < nsplit) ? biasA[col] : biasB[col - nsplit];
#pragma unroll
            for (int rg = 0; rg < 4; rg++) {
                int row = m0 + mq + i * 16 + lr + rg;
                float v = acc[i][j][rg] + bv;
                if (relu) v = fmaxf(v, 0.f);
                out[(size_t)row * N + col] = f2bf(v);
            }
        }
}

// ---------------------------------------------------------------------------
// GRU: persistent, 16 WGs x 512 threads, 16 batch rows per WG.
// Wave w (of 8) owns gh columns {rho*256 + w*32 + s*16 + [0,16)} for
// rho in {r,z,n}, s in {0,1}: B-fragments Bf[rho*2+s][ks] register-resident.
// h tile [16][256] bf16 in LDS; gi[t] double-buffered in LDS.
// Per step: reset-if-done -> barrier -> 8 ksteps x 6 MFMA -> barrier ->
// elementwise gate math (fp32) -> write h (LDS) + y (global).
// ---------------------------------------------------------------------------
__global__ __launch_bounds__(512, 2) void k_gru(
    const unsigned short* __restrict__ gi, const unsigned short* __restrict__ WhF,
    const int* __restrict__ dones, const float* __restrict__ h0,
    const float* __restrict__ bhn, unsigned short* __restrict__ y)
{
    __shared__ unsigned short hT[16][264];        // 528 B rows: 16B-aligned, 2-way banks
    __shared__ unsigned short giT[2][16][776];
    const int tid = threadIdx.x, w = tid >> 6, L = tid & 63;
    const int b0 = blockIdx.x * 16;
    const int rowg = L >> 4, lc = L & 15;

    short8 Bf[6][8];
#pragma unroll
    for (int i6 = 0; i6 < 6; i6++)
#pragma unroll
        for (int ks = 0; ks < 8; ks++)
            Bf[i6][ks] = *(const short8*)(WhF + ((((size_t)w * 6 + i6) * 8 + ks) * 64 + L) * 8);

    {   // init h from input carry
        int e = tid * 8, row = e >> 8, col = e & 255;
#pragma unroll
        for (int c = 0; c < 8; c++)
            hT[row][col + c] = f2bf(h0[(b0 + row) * 256 + col + c]);
    }
    const float bh0 = bhn[w * 32 + lc], bh1 = bhn[w * 32 + 16 + lc];

    const int prow = tid >> 5, pcol = (tid & 31) * 24;  // gi staging: 24 bf16/thread
    {
        const unsigned short* src = gi + ((size_t)(b0 + prow) * 768 + pcol);
        *(short8*)&giT[0][prow][pcol]      = *(const short8*)(src);
        *(short8*)&giT[0][prow][pcol + 8]  = *(const short8*)(src + 8);
        *(short8*)&giT[0][prow][pcol + 16] = *(const short8*)(src + 16);
    }
    __syncthreads();

    for (int t = 0; t < T_DIM; t++) {
        const int cur = t & 1, nxt = cur ^ 1;
        // prefetch gi[t+1] into registers
        int tp = (t + 1 < T_DIM) ? (t + 1) : (T_DIM - 1);
        const unsigned short* gsrc = gi + ((size_t)(tp * 256 + b0 + prow) * 768 + pcol);
        short8 g0 = *(const short8*)(gsrc);
        short8 g1 = *(const short8*)(gsrc + 8);
        short8 g2 = *(const short8*)(gsrc + 16);

        // per-step reset: each lane owns exactly its own h elements
#pragma unroll
        for (int r = 0; r < 4; r++) {
            int row = rowg * 4 + r;
            if (dones[t * 256 + b0 + row]) {
                hT[row][w * 32 + lc]      = 0;
                hT[row][w * 32 + 16 + lc] = 0;
            }
        }
        __syncthreads();   // h stable before cross-wave A-fragment reads

        f32x4 acc0 = 0, acc1 = 0, acc2 = 0, acc3 = 0, acc4 = 0, acc5 = 0;
#pragma unroll
        for (int ks = 0; ks < 8; ks++) {
            short8 a = *(const short8*)&hT[lc][ks * 32 + rowg * 8];
            acc0 = __builtin_amdgcn_mfma_f32_16x16x32_bf16(a, Bf[0][ks], acc0, 0, 0, 0);
            acc1 = __builtin_amdgcn_mfma_f32_16x16x32_bf16(a, Bf[1][ks], acc1, 0, 0, 0);
            acc2 = __builtin_amdgcn_mfma_f32_16x16x32_bf16(a, Bf[2][ks], acc2, 0, 0, 0);
            acc3 = __builtin_amdgcn_mfma_f32_16x16x32_bf16(a, Bf[3][ks], acc3, 0, 0, 0);
            acc4 = __builtin_amdgcn_mfma_f32_16x16x32_bf16(a, Bf[4][ks], acc4, 0, 0, 0);
            acc5 = __builtin_amdgcn_mfma_f32_16x16x32_bf16(a, Bf[5][ks], acc5, 0, 0, 0);
        }
        // park prefetched gi[t+1] into the other LDS buffer
        *(short8*)&giT[nxt][prow][pcol]      = g0;
        *(short8*)&giT[nxt][prow][pcol + 8]  = g1;
        *(short8*)&giT[nxt][prow][pcol + 16] = g2;
        __syncthreads();   // A reads done -> safe to overwrite h; gi[t+1] ready

#pragma unroll
        for (int s = 0; s < 2; s++) {
            const int j = w * 32 + s * 16 + lc;
            f32x4 hrv = s ? acc1 : acc0;
            f32x4 hzv = s ? acc3 : acc2;
            f32x4 hnv = s ? acc5 : acc4;
            float bh = s ? bh1 : bh0;
#pragma unroll
            for (int r = 0; r < 4; r++) {
                int row = rowg * 4 + r;
                float ir  = bf2f(giT[cur][row][j]);
                float iz  = bf2f(giT[cur][row][256 + j]);
                float inn = bf2f(giT[cur][row][512 + j]);
                float ho  = bf2f(hT[row][j]);
                float rg = 1.f / (1.f + __expf(-(ir + hrv[r])));
                float z  = 1.f / (1.f + __expf(-(iz + hzv[r])));
                float ex = __expf(2.f * (inn + rg * (hnv[r] + bh)));
                float n  = 1.f - 2.f / (ex + 1.f);          // tanh, inf-safe
                float hn2 = (1.f - z) * n + z * ho;
                unsigned short hb = f2bf(hn2);
                hT[row][j] = hb;
                y[((size_t)(t * 256 + b0 + row)) * 256 + j] = hb;
            }
        }
        // next iteration's first barrier protects these h writes
    }
}

// ---------------------------------------------------------------------------
// G4: logits = a @ WlogT^T + blog, masked.  M=TB, N=160(pad of 144), K=256.
// A = ac (lda=512, first 256 cols).  Writes fp32 directly to d_out regions.
// ---------------------------------------------------------------------------
__global__ __launch_bounds__(256, 2) void k_logits(
    const unsigned short* __restrict__ ac, const unsigned short* __restrict__ Bt,
    const float* __restrict__ blog,
    const int* __restrict__ av1, const int* __restrict__ av2,
    const int* __restrict__ av3, const int* __restrict__ av4,
    float* __restrict__ outp)
{
    __shared__ unsigned short As[128][72];
    __shared__ unsigned short Bs[160][72];
    const int tid = threadIdx.x, w = tid >> 6, L = tid & 63;
    const int m0 = blockIdx.x * 128;
    const int sr = tid >> 1, sh = (tid & 1) * 32;
    const int lc = L & 15, lq8 = (L >> 4) * 8, lr = (L >> 4) * 4;

    f32x4 acc[2][10];
#pragma unroll
    for (int i = 0; i < 2; i++)
#pragma unroll
        for (int j = 0; j < 10; j++) acc[i][j] = 0;

    const unsigned short* Ag = ac + (size_t)(m0 + sr) * 512 + sh;

    for (int kt = 0; kt < 256; kt += 64) {
#pragma unroll
        for (int c = 0; c < 32; c += 8)
            *(short8*)&As[sr][sh + c] = *(const short8*)(Ag + kt + c);
        for (int u = tid; u < 320; u += 256) {
            int br = u >> 1, bh2 = (u & 1) * 32;
#pragma unroll
            for (int c = 0; c < 32; c += 8)
                *(short8*)&Bs[br][bh2 + c] = *(const short8*)(Bt + (size_t)br * 256 + kt + bh2 + c);
        }
        __syncthreads();
#pragma unroll
        for (int ks = 0; ks < 2; ks++) {
            short8 a[2], b[10];
#pragma unroll
            for (int i = 0; i < 2; i++)
                a[i] = *(const short8*)&As[w * 32 + i * 16 + lc][ks * 32 + lq8];
#pragma unroll
            for (int j = 0; j < 10; j++)
                b[j] = *(const short8*)&Bs[j * 16 + lc][ks * 32 + lq8];
#pragma unroll
            for (int i = 0; i < 2; i++)
#pragma unroll
                for (int j = 0; j < 10; j++)
                    acc[i][j] = __builtin_amdgcn_mfma_f32_16x16x32_bf16(a[i], b[j], acc[i][j], 0, 0, 0);
        }
        __syncthreads();
    }
#pragma unroll
    for (int j = 0; j < 10; j++) {
        int col = j * 16 + lc;
        if (col >= 144) continue;
        int gbase, adim; const int* av; size_t obase;
        if      (col < 32) { gbase = 0;  adim = 32; av = av1; obase = OUT_LC1; }
        else if (col < 64) { gbase = 32; adim = 32; av = av2; obase = OUT_LC2; }
        else if (col < 80) { gbase = 64; adim = 16; av = av3; obase = OUT_MC;  }
        else               { gbase = 80; adim = 64; av = av4; obase = OUT_HINT;}
        int cof = col - gbase;
        float bv = blog[col];
#pragma unroll
        for (int i = 0; i < 2; i++)
#pragma unroll
            for (int rg = 0; rg < 4; rg++) {
                int R = m0 + w * 32 + i * 16 + lr + rg;
                float v = acc[i][j][rg] + bv;
                int a_ = av[(size_t)R * adim + cof];
                v -= (1.f - (float)a_) * 1e10f;
                outp[obase + (size_t)R * adim + cof] = v;
            }
    }
}

// ---------------------------------------------------------------------------
// G5: critic[R] = relu_c[R,:] . W_c2 + b_c2.  One wave per row (dot-256).
// ---------------------------------------------------------------------------
__global__ __launch_bounds__(256, 4) void k_critic(
    const unsigned short* __restrict__ ac, const float* __restrict__ W_c2,
    const float* __restrict__ b_c2, float* __restrict__ outp)
{
    const int tid = threadIdx.x, w = tid >> 6, L = tid & 63;
    f32x4 wv = *(const f32x4*)(W_c2 + L * 4);
    float bb = b_c2[0];
    int base = blockIdx.x * 64 + w * 16;
    for (int rr = 0; rr < 16; rr++) {
        int R = base + rr;
        const unsigned short* p = ac + (size_t)R * 512 + 256 + L * 4;
        float s = bf2f(p[0]) * wv[0] + bf2f(p[1]) * wv[1] +
                  bf2f(p[2]) * wv[2] + bf2f(p[3]) * wv[3];
#pragma unroll
        for (int o = 32; o > 0; o >>= 1) s += __shfl_down(s, o);
        if (L == 0) outp[OUT_CRIT + R] = s + bb;
    }
}

// final hidden = y[T-1] -> fp32
__global__ __launch_bounds__(256, 4) void k_hidden(
    const unsigned short* __restrict__ y, float* __restrict__ outp)
{
    int i = blockIdx.x * 256 + threadIdx.x;
    outp[OUT_HID + i] = bf2f(y[(size_t)511 * 65536 + i]);
}

// ---------------------------------------------------------------------------
extern "C" void kernel_launch(void* const* d_in, const int* in_sizes, int n_in,
                              void* d_out, int out_size, void* d_ws, size_t ws_size,
                              hipStream_t stream)
{
    const float* hidden = (const float*)d_in[0];
    const float* obs    = (const float*)d_in[1];
    const int*   dones  = (const int*)d_in[2];
    const int*   av1    = (const int*)d_in[3];
    const int*   av2    = (const int*)d_in[4];
    const int*   av3    = (const int*)d_in[5];
    const int*   av4    = (const int*)d_in[6];
    const float* W_emb  = (const float*)d_in[7];
    const float* b_emb  = (const float*)d_in[8];
    const float* Wi     = (const float*)d_in[9];
    const float* bi     = (const float*)d_in[10];
    const float* Wh     = (const float*)d_in[11];
    const float* bhn    = (const float*)d_in[12];
    const float* W_a    = (const float*)d_in[13];
    const float* b_a    = (const float*)d_in[14];
    const float* W_lc1  = (const float*)d_in[15];
    const float* b_lc1  = (const float*)d_in[16];
    const float* W_lc2  = (const float*)d_in[17];
    const float* b_lc2  = (const float*)d_in[18];
    const float* W_mc   = (const float*)d_in[19];
    const float* b_mc   = (const float*)d_in[20];
    const float* W_hint = (const float*)d_in[21];
    const float* b_hint = (const float*)d_in[22];
    const float* W_c1   = (const float*)d_in[23];
    const float* b_c1   = (const float*)d_in[24];
    const float* W_c2   = (const float*)d_in[25];
    const float* b_c2   = (const float*)d_in[26];

    char* ws = (char*)d_ws;
    unsigned short* WembT = (unsigned short*)(ws + 0);
    unsigned short* WiT   = (unsigned short*)(ws + 262144);
    unsigned short* WhF   = (unsigned short*)(ws + 655360);
    unsigned short* WacT  = (unsigned short*)(ws + 1048576);
    unsigned short* WlogT = (unsigned short*)(ws + 1310720);
    float*          blog  = (float*)(ws + 1392640);
    // emb (TB x 256 bf16, 67 MB) and ac (TB x 512 bf16, 134 MB) share a
    // region: emb is dead before G3 writes ac.
    unsigned short* emb   = (unsigned short*)(ws + 1393664);
    unsigned short* ac    = emb;
    unsigned short* gibuf = (unsigned short*)(ws + 135611392);
    unsigned short* ybuf  = (unsigned short*)(ws + 336937984);
    float* outp = (float*)d_out;

    k_prep<<<2721, 256, 0, stream>>>(W_emb, Wi, Wh, W_a, W_c1, W_lc1, W_lc2,
                                     W_mc, W_hint, b_lc1, b_lc2, b_mc, b_hint,
                                     WembT, WiT, WhF, WacT, WlogT, blog);
    k_gemm_obs<<<dim3(1024, 2), 256, 0, stream>>>(obs, WembT, b_emb, emb);
    k_gemm_bf<<<dim3(1024, 6), 256, 0, stream>>>(emb, WiT, bi, bi, 768, 0, 768, gibuf);
    k_gru<<<16, 512, 0, stream>>>(gibuf, WhF, dones, hidden, bhn, ybuf);
    k_gemm_bf<<<dim3(1024, 4), 256, 0, stream>>>(ybuf, WacT, b_a, b_c1, 256, 1, 512, ac);
    k_logits<<<1024, 256, 0, stream>>>(ac, WlogT, blog, av1, av2, av3, av4, outp);
    k_critic<<<2048, 256, 0, stream>>>(ac, W_c2, b_c2, outp);
    k_hidden<<<256, 256, 0, stream>>>(ybuf, outp);
}

// Round 2
// 1499.614 us; speedup vs baseline: 1.7990x; 1.7990x over previous
//
#include <hip/hip_runtime.h>
#include <stdint.h>

// ---------------------------------------------------------------------------
// ActorCriticRNN on MI355X.
//   prep:  weights -> bf16 (B^T layout), Wh -> MFMA-fragment-linear.
//   G1:    emb = relu(obs @ W_emb + b_emb)             bf16 MFMA
//   G2:    gi  = emb @ Wi + bi (hoisted out of scan)   bf16 MFMA
//   GRU:   chunk-parallel: dones (p=0.5) reset h, so chunks of 32 steps
//          speculated with carry=0 are correct from each row's first done.
//          Main: 256 WGs (16 batch-tiles x 16 chunks). Fixup: 16 WGs redo
//          only the pre-first-done prefix (~5 steps/chunk) with true carry.
//          Wh register-resident (48 B-frags/thread); h double-buffered in
//          LDS -> ONE barrier/step; dones in LDS bitmask.
//   G3:    [a|c] = relu(y @ [W_a|W_c1] + b)            bf16 MFMA
//   G4:    logits masked by avail; G5: critic dot; out0: hidden = y[T-1].
// ---------------------------------------------------------------------------

typedef short short8 __attribute__((ext_vector_type(8)));
typedef float f32x4  __attribute__((ext_vector_type(4)));

#define T_DIM 512
#define CHUNK 32
#define NCH   16

// output offsets (fp32 elements)
#define OUT_HID  ((size_t)0)
#define OUT_LC1  ((size_t)65536)
#define OUT_LC2  ((size_t)4259840)
#define OUT_MC   ((size_t)8454144)
#define OUT_HINT ((size_t)10551296)
#define OUT_CRIT ((size_t)18939904)

__device__ __forceinline__ unsigned short f2bf(float f) {
    unsigned u = __float_as_uint(f);
    u += 0x7fffu + ((u >> 16) & 1u);          // round-to-nearest-even
    return (unsigned short)(u >> 16);
}
__device__ __forceinline__ float bf2f(unsigned short h) {
    return __uint_as_float(((unsigned)h) << 16);
}

__device__ __forceinline__ unsigned short gru_cell(
    float ir, float iz, float inn, float ho,
    float hrv, float hzv, float hnv, float bh)
{
    float rg = 1.f / (1.f + __expf(-(ir + hrv)));
    float z  = 1.f / (1.f + __expf(-(iz + hzv)));
    float ex = __expf(2.f * (inn + rg * (hnv + bh)));
    float n  = 1.f - 2.f / (ex + 1.f);        // tanh, inf-safe
    return f2bf((1.f - z) * n + z * ho);
}

// ---------------------------------------------------------------------------
// prep (unchanged from R1 — verified correct)
// ---------------------------------------------------------------------------
__global__ __launch_bounds__(256, 4) void k_prep(
    const float* __restrict__ W_emb, const float* __restrict__ Wi,
    const float* __restrict__ Wh,    const float* __restrict__ W_a,
    const float* __restrict__ W_c1,  const float* __restrict__ W_lc1,
    const float* __restrict__ W_lc2, const float* __restrict__ W_mc,
    const float* __restrict__ W_hint,
    const float* __restrict__ b_lc1, const float* __restrict__ b_lc2,
    const float* __restrict__ b_mc,  const float* __restrict__ b_hint,
    unsigned short* __restrict__ WembT, unsigned short* __restrict__ WiT,
    unsigned short* __restrict__ WhF,   unsigned short* __restrict__ WacT,
    unsigned short* __restrict__ WlogT, float* __restrict__ blog)
{
    int i = blockIdx.x * 256 + threadIdx.x;
    if (i < 131072) {                         // WembT[n][k] = W_emb[k][n]
        int n = i >> 9, k = i & 511;
        WembT[i] = f2bf(W_emb[k * 256 + n]);
        return;
    }
    i -= 131072;
    if (i < 196608) {                         // WiT[n][k] = Wi[k][n]
        int n = i >> 8, k = i & 255;
        WiT[i] = f2bf(Wi[k * 768 + n]);
        return;
    }
    i -= 196608;
    if (i < 196608) {                         // Wh fragment-linear
        int jj = i & 7, L = (i >> 3) & 63, ks = (i >> 9) & 7, rest = i >> 12;
        int w = rest / 6, i6 = rest % 6, rho = i6 >> 1, s = i6 & 1;
        int k   = ks * 32 + ((L >> 4) << 3) + jj;
        int col = rho * 256 + w * 32 + s * 16 + (L & 15);
        WhF[i] = f2bf(Wh[k * 768 + col]);
        return;
    }
    i -= 196608;
    if (i < 131072) {                         // WacT
        int n = i >> 8, k = i & 255;
        WacT[i] = f2bf(n < 256 ? W_a[k * 256 + n] : W_c1[k * 256 + (n - 256)]);
        return;
    }
    i -= 131072;
    if (i < 40960) {                          // WlogT (N padded to 160)
        int n = i >> 8, k = i & 255;
        float v;
        if      (n < 32)  v = W_lc1[k * 32 + n];
        else if (n < 64)  v = W_lc2[k * 32 + (n - 32)];
        else if (n < 80)  v = W_mc [k * 16 + (n - 64)];
        else if (n < 144) v = W_hint[k * 64 + (n - 80)];
        else              v = 0.f;
        WlogT[i] = f2bf(v);
        return;
    }
    i -= 40960;
    if (i < 160) {
        float v;
        if      (i < 32)  v = b_lc1[i];
        else if (i < 64)  v = b_lc2[i - 32];
        else if (i < 80)  v = b_mc [i - 64];
        else if (i < 144) v = b_hint[i - 80];
        else              v = 0.f;
        blog[i] = v;
    }
}

// ---------------------------------------------------------------------------
// G1: emb = relu(obs @ W_emb + b_emb)  (unchanged)
// ---------------------------------------------------------------------------
__global__ __launch_bounds__(256, 3) void k_gemm_obs(
    const float* __restrict__ A, const unsigned short* __restrict__ Bt,
    const float* __restrict__ bias, unsigned short* __restrict__ out)
{
    __shared__ unsigned short As[128][72];
    __shared__ unsigned short Bs[128][72];
    const int tid = threadIdx.x, w = tid >> 6, L = tid & 63;
    const int mq = (w >> 1) * 64, nq = (w & 1) * 64;
    const int m0 = blockIdx.x * 128, n0 = blockIdx.y * 128;
    const int sr = tid >> 1, sh = (tid & 1) * 32;
    const int lc = L & 15, lq8 = (L >> 4) * 8, lr = (L >> 4) * 4;

    f32x4 acc[4][4];
#pragma unroll
    for (int i = 0; i < 4; i++)
#pragma unroll
        for (int j = 0; j < 4; j++) acc[i][j] = 0;

    const float* Ag = A + (size_t)(m0 + sr) * 512 + sh;
    const unsigned short* Bg = Bt + (size_t)(n0 + sr) * 512 + sh;

    for (int kt = 0; kt < 512; kt += 64) {
#pragma unroll
        for (int c = 0; c < 32; c += 8) {
            f32x4 v0 = *(const f32x4*)(Ag + kt + c);
            f32x4 v1 = *(const f32x4*)(Ag + kt + c + 4);
            short8 pk;
            pk[0] = (short)f2bf(v0[0]); pk[1] = (short)f2bf(v0[1]);
            pk[2] = (short)f2bf(v0[2]); pk[3] = (short)f2bf(v0[3]);
            pk[4] = (short)f2bf(v1[0]); pk[5] = (short)f2bf(v1[1]);
            pk[6] = (short)f2bf(v1[2]); pk[7] = (short)f2bf(v1[3]);
            *(short8*)&As[sr][sh + c] = pk;
            *(short8*)&Bs[sr][sh + c] = *(const short8*)(Bg + kt + c);
        }
        __syncthreads();
#pragma unroll
        for (int ks = 0; ks < 2; ks++) {
            short8 a[4], b[4];
#pragma unroll
            for (int i = 0; i < 4; i++)
                a[i] = *(const short8*)&As[mq + i * 16 + lc][ks * 32 + lq8];
#pragma unroll
            for (int j = 0; j < 4; j++)
                b[j] = *(const short8*)&Bs[nq + j * 16 + lc][ks * 32 + lq8];
#pragma unroll
            for (int i = 0; i < 4; i++)
#pragma unroll
                for (int j = 0; j < 4; j++)
                    acc[i][j] = __builtin_amdgcn_mfma_f32_16x16x32_bf16(a[i], b[j], acc[i][j], 0, 0, 0);
        }
        __syncthreads();
    }
#pragma unroll
    for (int i = 0; i < 4; i++)
#pragma unroll
        for (int j = 0; j < 4; j++) {
            int col = n0 + nq + j * 16 + lc;
            float bv = bias[col];
#pragma unroll
            for (int rg = 0; rg < 4; rg++) {
                int row = m0 + mq + i * 16 + lr + rg;
                float v = acc[i][j][rg] + bv;
                v = fmaxf(v, 0.f);
                out[(size_t)row * 256 + col] = f2bf(v);
            }
        }
}

// ---------------------------------------------------------------------------
// Generic bf16-A GEMM, K=256  (unchanged)
// ---------------------------------------------------------------------------
__global__ __launch_bounds__(256, 3) void k_gemm_bf(
    const unsigned short* __restrict__ A, const unsigned short* __restrict__ Bt,
    const float* __restrict__ biasA, const float* __restrict__ biasB,
    int nsplit, int relu, int N, unsigned short* __restrict__ out)
{
    __shared__ unsigned short As[128][72];
    __shared__ unsigned short Bs[128][72];
    const int tid = threadIdx.x, w = tid >> 6, L = tid & 63;
    const int mq = (w >> 1) * 64, nq = (w & 1) * 64;
    const int m0 = blockIdx.x * 128, n0 = blockIdx.y * 128;
    const int sr = tid >> 1, sh = (tid & 1) * 32;
    const int lc = L & 15, lq8 = (L >> 4) * 8, lr = (L >> 4) * 4;

    f32x4 acc[4][4];
#pragma unroll
    for (int i = 0; i < 4; i++)
#pragma unroll
        for (int j = 0; j < 4; j++) acc[i][j] = 0;

    const unsigned short* Ag = A + (size_t)(m0 + sr) * 256 + sh;
    const unsigned short* Bg = Bt + (size_t)(n0 + sr) * 256 + sh;

    for (int kt = 0; kt < 256; kt += 64) {
#pragma unroll
        for (int c = 0; c < 32; c += 8) {
            *(short8*)&As[sr][sh + c] = *(const short8*)(Ag + kt + c);
            *(short8*)&Bs[sr][sh + c] = *(const short8*)(Bg + kt + c);
        }
        __syncthreads();
#pragma unroll
        for (int ks = 0; ks < 2; ks++) {
            short8 a[4], b[4];
#pragma unroll
            for (int i = 0; i < 4; i++)
                a[i] = *(const short8*)&As[mq + i * 16 + lc][ks * 32 + lq8];
#pragma unroll
            for (int j = 0; j < 4; j++)
                b[j] = *(const short8*)&Bs[nq + j * 16 + lc][ks * 32 + lq8];
#pragma unroll
            for (int i = 0; i < 4; i++)
#pragma unroll
                for (int j = 0; j < 4; j++)
                    acc[i][j] = __builtin_amdgcn_mfma_f32_16x16x32_bf16(a[i], b[j], acc[i][j], 0, 0, 0);
        }
        __syncthreads();
    }
#pragma unroll
    for (int i = 0; i < 4; i++)
#pragma unroll
        for (int j = 0; j < 4; j++) {
            int col = n0 + nq + j * 16 + lc;
            float bv = (col < nsplit) ? biasA[col] : biasB[col - nsplit];
#pragma unroll
            for (int rg = 0; rg < 4; rg++) {
                int row = m0 + mq + i * 16 + lr + rg;
                float v = acc[i][j][rg] + bv;
                if (relu) v = fmaxf(v, 0.f);
                out[(size_t)row * N + col] = f2bf(v);
            }
        }
}

// ---------------------------------------------------------------------------
// GRU main pass: 256 WGs = (batch-tile g = x&15) x (chunk c = x>>4).
// Speculates carry-in = 0 for c>0 (chunk 0 uses true h0). Stores h_end[c].
// One barrier per step: h double-buffered; done-reset folded into writes.
// gi read straight from global in the epilogue (coalesced across WG).
// ---------------------------------------------------------------------------
__global__ __launch_bounds__(512, 1) void k_gru_main(
    const unsigned short* __restrict__ gi, const unsigned short* __restrict__ WhF,
    const int* __restrict__ dones, const float* __restrict__ h0,
    const float* __restrict__ bhn, unsigned short* __restrict__ y,
    unsigned short* __restrict__ hend)
{
    __shared__ unsigned short hT[2][16][264];
    __shared__ unsigned int rowbits[16];      // bit t' of dones for each row
    const int tid = threadIdx.x, w = tid >> 6, L = tid & 63;
    const int g = blockIdx.x & 15, c = blockIdx.x >> 4;
    const int b0 = g * 16, t0 = c * CHUNK;
    const int rowg = L >> 4, lc = L & 15;

    short8 Bf[6][8];
#pragma unroll
    for (int i6 = 0; i6 < 6; i6++)
#pragma unroll
        for (int ks = 0; ks < 8; ks++)
            Bf[i6][ks] = *(const short8*)(WhF + ((((size_t)w * 6 + i6) * 8 + ks) * 64 + L) * 8);

    const float bh0 = bhn[w * 32 + lc], bh1 = bhn[w * 32 + 16 + lc];

    // build dones bitmask for this chunk
    if (tid < 16) rowbits[tid] = 0;
    __syncthreads();
    {
        int tp = tid >> 4, r = tid & 15;
        if (dones[(t0 + tp) * 256 + b0 + r]) atomicOr(&rowbits[r], 1u << tp);
    }
    __syncthreads();

    unsigned rbr[4];
#pragma unroll
    for (int r = 0; r < 4; r++) rbr[r] = rowbits[rowg * 4 + r];

    // init h: c==0 -> h0 with done[0] reset; c>0 -> speculative 0
    {
        int hrow = tid >> 5, hcol = (tid & 31) * 8;
        bool rz = (rowbits[hrow] & 1u) != 0;
#pragma unroll
        for (int cc = 0; cc < 8; cc++) {
            unsigned short v = 0;
            if (c == 0 && !rz) v = f2bf(h0[(b0 + hrow) * 256 + hcol + cc]);
            hT[0][hrow][hcol + cc] = v;
        }
    }
    __syncthreads();

#pragma unroll 2
    for (int tp = 0; tp < CHUNK; tp++) {
        const int cur = tp & 1, nxt = cur ^ 1;
        const int t = t0 + tp;

        f32x4 acc0 = 0, acc1 = 0, acc2 = 0, acc3 = 0, acc4 = 0, acc5 = 0;
#pragma unroll
        for (int ks = 0; ks < 8; ks++) {
            short8 a = *(const short8*)&hT[cur][lc][ks * 32 + rowg * 8];
            acc0 = __builtin_amdgcn_mfma_f32_16x16x32_bf16(a, Bf[0][ks], acc0, 0, 0, 0);
            acc1 = __builtin_amdgcn_mfma_f32_16x16x32_bf16(a, Bf[1][ks], acc1, 0, 0, 0);
            acc2 = __builtin_amdgcn_mfma_f32_16x16x32_bf16(a, Bf[2][ks], acc2, 0, 0, 0);
            acc3 = __builtin_amdgcn_mfma_f32_16x16x32_bf16(a, Bf[3][ks], acc3, 0, 0, 0);
            acc4 = __builtin_amdgcn_mfma_f32_16x16x32_bf16(a, Bf[4][ks], acc4, 0, 0, 0);
            acc5 = __builtin_amdgcn_mfma_f32_16x16x32_bf16(a, Bf[5][ks], acc5, 0, 0, 0);
        }

        const unsigned short* gb = gi + (size_t)(t * 256 + b0) * 768;
        unsigned short* yb = y + (size_t)(t * 256 + b0) * 256;
#pragma unroll
        for (int s = 0; s < 2; s++) {
            const int j = w * 32 + s * 16 + lc;
            f32x4 hrv = s ? acc1 : acc0;
            f32x4 hzv = s ? acc3 : acc2;
            f32x4 hnv = s ? acc5 : acc4;
            float bh = s ? bh1 : bh0;
#pragma unroll
            for (int r = 0; r < 4; r++) {
                int row = rowg * 4 + r;
                float ir  = bf2f(gb[row * 768 + j]);
                float iz  = bf2f(gb[row * 768 + 256 + j]);
                float inn = bf2f(gb[row * 768 + 512 + j]);
                float ho  = bf2f(hT[cur][row][j]);
                unsigned short hb = gru_cell(ir, iz, inn, ho, hrv[r], hzv[r], hnv[r], bh);
                yb[row * 256 + j] = hb;
                if (tp < CHUNK - 1) {
                    hT[nxt][row][j] = ((rbr[r] >> (tp + 1)) & 1u) ? (unsigned short)0 : hb;
                } else {
                    hend[((size_t)c * 256 + b0 + row) * 256 + j] = hb;   // raw carry-out
                }
            }
        }
        __syncthreads();
    }
}

// ---------------------------------------------------------------------------
// GRU fixup: 16 WGs, one per batch-tile, sequential over chunks 1..15.
// Recomputes only steps before each row's first done (E[max over 16 rows]~5),
// overwriting y; splices speculative h_end for rows that saw a done.
// Worst case (no dones) degrades to full recompute — still correct.
// ---------------------------------------------------------------------------
__global__ __launch_bounds__(512, 1) void k_gru_fix(
    const unsigned short* __restrict__ gi, const unsigned short* __restrict__ WhF,
    const int* __restrict__ dones, const float* __restrict__ bhn,
    const unsigned short* __restrict__ hend, unsigned short* __restrict__ y)
{
    __shared__ unsigned short hT[2][16][264];
    __shared__ unsigned int rowbits[16];
    __shared__ int sh_fd[16];
    const int tid = threadIdx.x, w = tid >> 6, L = tid & 63;
    const int b0 = blockIdx.x * 16;
    const int rowg = L >> 4, lc = L & 15;
    const int hrow = tid >> 5, hcol = (tid & 31) * 8;

    short8 Bf[6][8];
#pragma unroll
    for (int i6 = 0; i6 < 6; i6++)
#pragma unroll
        for (int ks = 0; ks < 8; ks++)
            Bf[i6][ks] = *(const short8*)(WhF + ((((size_t)w * 6 + i6) * 8 + ks) * 64 + L) * 8);

    const float bh0 = bhn[w * 32 + lc], bh1 = bhn[w * 32 + 16 + lc];

    // carry = corrected end of chunk 0 (chunk 0 speculation used true h0)
    *(short8*)&hT[0][hrow][hcol] =
        *(const short8*)(hend + (size_t)(b0 + hrow) * 256 + hcol);
    int cur = 0;

    for (int c = 1; c < NCH; c++) {
        const int t0 = c * CHUNK;
        if (tid < 16) rowbits[tid] = 0;
        __syncthreads();
        {
            int tp = tid >> 4, r = tid & 15;
            if (dones[(t0 + tp) * 256 + b0 + r]) atomicOr(&rowbits[r], 1u << tp);
        }
        __syncthreads();
        if (tid < 16) {
            unsigned m = rowbits[tid];
            sh_fd[tid] = m ? __builtin_ctz(m) : CHUNK;
        }
        __syncthreads();

        int maxfix = 0;
        unsigned rbr[4]; int fdr[4];
#pragma unroll
        for (int r = 0; r < 16; r++) maxfix = max(maxfix, sh_fd[r]);
#pragma unroll
        for (int r = 0; r < 4; r++) {
            rbr[r] = rowbits[rowg * 4 + r];
            fdr[r] = sh_fd[rowg * 4 + r];
        }
        // apply this chunk's step-0 reset to the carry
        if (rowbits[hrow] & 1u) {
#pragma unroll
            for (int cc = 0; cc < 8; cc++) hT[cur][hrow][hcol + cc] = 0;
        }
        __syncthreads();

        for (int tp = 0; tp < maxfix; tp++) {
            const int nxt = cur ^ 1;
            const int t = t0 + tp;

            f32x4 acc0 = 0, acc1 = 0, acc2 = 0, acc3 = 0, acc4 = 0, acc5 = 0;
#pragma unroll
            for (int ks = 0; ks < 8; ks++) {
                short8 a = *(const short8*)&hT[cur][lc][ks * 32 + rowg * 8];
                acc0 = __builtin_amdgcn_mfma_f32_16x16x32_bf16(a, Bf[0][ks], acc0, 0, 0, 0);
                acc1 = __builtin_amdgcn_mfma_f32_16x16x32_bf16(a, Bf[1][ks], acc1, 0, 0, 0);
                acc2 = __builtin_amdgcn_mfma_f32_16x16x32_bf16(a, Bf[2][ks], acc2, 0, 0, 0);
                acc3 = __builtin_amdgcn_mfma_f32_16x16x32_bf16(a, Bf[3][ks], acc3, 0, 0, 0);
                acc4 = __builtin_amdgcn_mfma_f32_16x16x32_bf16(a, Bf[4][ks], acc4, 0, 0, 0);
                acc5 = __builtin_amdgcn_mfma_f32_16x16x32_bf16(a, Bf[5][ks], acc5, 0, 0, 0);
            }

            const unsigned short* gb = gi + (size_t)(t * 256 + b0) * 768;
            unsigned short* yb = y + (size_t)(t * 256 + b0) * 256;
#pragma unroll
            for (int s = 0; s < 2; s++) {
                const int j = w * 32 + s * 16 + lc;
                f32x4 hrv = s ? acc1 : acc0;
                f32x4 hzv = s ? acc3 : acc2;
                f32x4 hnv = s ? acc5 : acc4;
                float bh = s ? bh1 : bh0;
#pragma unroll
                for (int r = 0; r < 4; r++) {
                    int row = rowg * 4 + r;
                    float ir  = bf2f(gb[row * 768 + j]);
                    float iz  = bf2f(gb[row * 768 + 256 + j]);
                    float inn = bf2f(gb[row * 768 + 512 + j]);
                    float ho  = bf2f(hT[cur][row][j]);
                    unsigned short hb = gru_cell(ir, iz, inn, ho, hrv[r], hzv[r], hnv[r], bh);
                    if (tp < fdr[r]) yb[row * 256 + j] = hb;   // only fix wrong prefix
                    unsigned short hw = hb;
                    if (tp + 1 < CHUNK && ((rbr[r] >> (tp + 1)) & 1u)) hw = 0;
                    hT[nxt][row][j] = hw;
                }
            }
            __syncthreads();
            cur = nxt;
        }

        // splice: rows that saw a done have correct speculative h_end
        if (sh_fd[hrow] < CHUNK) {
            *(short8*)&hT[cur][hrow][hcol] =
                *(const short8*)(hend + ((size_t)c * 256 + b0 + hrow) * 256 + hcol);
        }
        __syncthreads();
    }
}

// ---------------------------------------------------------------------------
// G4: logits (unchanged)
// ---------------------------------------------------------------------------
__global__ __launch_bounds__(256, 2) void k_logits(
    const unsigned short* __restrict__ ac, const unsigned short* __restrict__ Bt,
    const float* __restrict__ blog,
    const int* __restrict__ av1, const int* __restrict__ av2,
    const int* __restrict__ av3, const int* __restrict__ av4,
    float* __restrict__ outp)
{
    __shared__ unsigned short As[128][72];
    __shared__ unsigned short Bs[160][72];
    const int tid = threadIdx.x, w = tid >> 6, L = tid & 63;
    const int m0 = blockIdx.x * 128;
    const int sr = tid >> 1, sh = (tid & 1) * 32;
    const int lc = L & 15, lq8 = (L >> 4) * 8, lr = (L >> 4) * 4;

    f32x4 acc[2][10];
#pragma unroll
    for (int i = 0; i < 2; i++)
#pragma unroll
        for (int j = 0; j < 10; j++) acc[i][j] = 0;

    const unsigned short* Ag = ac + (size_t)(m0 + sr) * 512 + sh;

    for (int kt = 0; kt < 256; kt += 64) {
#pragma unroll
        for (int c = 0; c < 32; c += 8)
            *(short8*)&As[sr][sh + c] = *(const short8*)(Ag + kt + c);
        for (int u = tid; u < 320; u += 256) {
            int br = u >> 1, bh2 = (u & 1) * 32;
#pragma unroll
            for (int c = 0; c < 32; c += 8)
                *(short8*)&Bs[br][bh2 + c] = *(const short8*)(Bt + (size_t)br * 256 + kt + bh2 + c);
        }
        __syncthreads();
#pragma unroll
        for (int ks = 0; ks < 2; ks++) {
            short8 a[2], b[10];
#pragma unroll
            for (int i = 0; i < 2; i++)
                a[i] = *(const short8*)&As[w * 32 + i * 16 + lc][ks * 32 + lq8];
#pragma unroll
            for (int j = 0; j < 10; j++)
                b[j] = *(const short8*)&Bs[j * 16 + lc][ks * 32 + lq8];
#pragma unroll
            for (int i = 0; i < 2; i++)
#pragma unroll
                for (int j = 0; j < 10; j++)
                    acc[i][j] = __builtin_amdgcn_mfma_f32_16x16x32_bf16(a[i], b[j], acc[i][j], 0, 0, 0);
        }
        __syncthreads();
    }
#pragma unroll
    for (int j = 0; j < 10; j++) {
        int col = j * 16 + lc;
        if (col >= 144) continue;
        int gbase, adim; const int* av; size_t obase;
        if      (col < 32) { gbase = 0;  adim = 32; av = av1; obase = OUT_LC1; }
        else if (col < 64) { gbase = 32; adim = 32; av = av2; obase = OUT_LC2; }
        else if (col < 80) { gbase = 64; adim = 16; av = av3; obase = OUT_MC;  }
        else               { gbase = 80; adim = 64; av = av4; obase = OUT_HINT;}
        int cof = col - gbase;
        float bv = blog[col];
#pragma unroll
        for (int i = 0; i < 2; i++)
#pragma unroll
            for (int rg = 0; rg < 4; rg++) {
                int R = m0 + w * 32 + i * 16 + lr + rg;
                float v = acc[i][j][rg] + bv;
                int a_ = av[(size_t)R * adim + cof];
                v -= (1.f - (float)a_) * 1e10f;
                outp[obase + (size_t)R * adim + cof] = v;
            }
    }
}

// ---------------------------------------------------------------------------
// G5: critic (unchanged)
// ---------------------------------------------------------------------------
__global__ __launch_bounds__(256, 4) void k_critic(
    const unsigned short* __restrict__ ac, const float* __restrict__ W_c2,
    const float* __restrict__ b_c2, float* __restrict__ outp)
{
    const int tid = threadIdx.x, w = tid >> 6, L = tid & 63;
    f32x4 wv = *(const f32x4*)(W_c2 + L * 4);
    float bb = b_c2[0];
    int base = blockIdx.x * 64 + w * 16;
    for (int rr = 0; rr < 16; rr++) {
        int R = base + rr;
        const unsigned short* p = ac + (size_t)R * 512 + 256 + L * 4;
        float s = bf2f(p[0]) * wv[0] + bf2f(p[1]) * wv[1] +
                  bf2f(p[2]) * wv[2] + bf2f(p[3]) * wv[3];
#pragma unroll
        for (int o = 32; o > 0; o >>= 1) s += __shfl_down(s, o);
        if (L == 0) outp[OUT_CRIT + R] = s + bb;
    }
}

__global__ __launch_bounds__(256, 4) void k_hidden(
    const unsigned short* __restrict__ y, float* __restrict__ outp)
{
    int i = blockIdx.x * 256 + threadIdx.x;
    outp[OUT_HID + i] = bf2f(y[(size_t)511 * 65536 + i]);
}

// ---------------------------------------------------------------------------
extern "C" void kernel_launch(void* const* d_in, const int* in_sizes, int n_in,
                              void* d_out, int out_size, void* d_ws, size_t ws_size,
                              hipStream_t stream)
{
    const float* hidden = (const float*)d_in[0];
    const float* obs    = (const float*)d_in[1];
    const int*   dones  = (const int*)d_in[2];
    const int*   av1    = (const int*)d_in[3];
    const int*   av2    = (const int*)d_in[4];
    const int*   av3    = (const int*)d_in[5];
    const int*   av4    = (const int*)d_in[6];
    const float* W_emb  = (const float*)d_in[7];
    const float* b_emb  = (const float*)d_in[8];
    const float* Wi     = (const float*)d_in[9];
    const float* bi     = (const float*)d_in[10];
    const float* Wh     = (const float*)d_in[11];
    const float* bhn    = (const float*)d_in[12];
    const float* W_a    = (const float*)d_in[13];
    const float* b_a    = (const float*)d_in[14];
    const float* W_lc1  = (const float*)d_in[15];
    const float* b_lc1  = (const float*)d_in[16];
    const float* W_lc2  = (const float*)d_in[17];
    const float* b_lc2  = (const float*)d_in[18];
    const float* W_mc   = (const float*)d_in[19];
    const float* b_mc   = (const float*)d_in[20];
    const float* W_hint = (const float*)d_in[21];
    const float* b_hint = (const float*)d_in[22];
    const float* W_c1   = (const float*)d_in[23];
    const float* b_c1   = (const float*)d_in[24];
    const float* W_c2   = (const float*)d_in[25];
    const float* b_c2   = (const float*)d_in[26];

    char* ws = (char*)d_ws;
    unsigned short* WembT = (unsigned short*)(ws + 0);
    unsigned short* WiT   = (unsigned short*)(ws + 262144);
    unsigned short* WhF   = (unsigned short*)(ws + 655360);
    unsigned short* WacT  = (unsigned short*)(ws + 1048576);
    unsigned short* WlogT = (unsigned short*)(ws + 1310720);
    float*          blog  = (float*)(ws + 1392640);
    // emb (TB x 256 bf16, 67 MB) / hend (2 MB) / ac (TB x 512 bf16, 134 MB)
    // share a region: emb dies after G2; hend lives only gru_main->gru_fix;
    // ac written by G3 after fixup.
    unsigned short* emb   = (unsigned short*)(ws + 1393664);
    unsigned short* hend  = emb;
    unsigned short* ac    = emb;
    unsigned short* gibuf = (unsigned short*)(ws + 135611392);
    unsigned short* ybuf  = (unsigned short*)(ws + 336937984);
    float* outp = (float*)d_out;

    k_prep<<<2721, 256, 0, stream>>>(W_emb, Wi, Wh, W_a, W_c1, W_lc1, W_lc2,
                                     W_mc, W_hint, b_lc1, b_lc2, b_mc, b_hint,
                                     WembT, WiT, WhF, WacT, WlogT, blog);
    k_gemm_obs<<<dim3(1024, 2), 256, 0, stream>>>(obs, WembT, b_emb, emb);
    k_gemm_bf<<<dim3(1024, 6), 256, 0, stream>>>(emb, WiT, bi, bi, 768, 0, 768, gibuf);
    k_gru_main<<<256, 512, 0, stream>>>(gibuf, WhF, dones, hidden, bhn, ybuf, hend);
    k_gru_fix<<<16, 512, 0, stream>>>(gibuf, WhF, dones, bhn, hend, ybuf);
    k_gemm_bf<<<dim3(1024, 4), 256, 0, stream>>>(ybuf, WacT, b_a, b_c1, 256, 1, 512, ac);
    k_logits<<<1024, 256, 0, stream>>>(ac, WlogT, blog, av1, av2, av3, av4, outp);
    k_critic<<<2048, 256, 0, stream>>>(ac, W_c2, b_c2, outp);
    k_hidden<<<256, 256, 0, stream>>>(ybuf, outp);
}